// Round 7
// baseline (121.345 us; speedup 1.0000x reference)
//
#include <hip/hip_runtime.h>
#include <hip/hip_fp16.h>
#include <math.h>

#define NN 1024
#define CC 200
#define AA 256

static constexpr float P_EXP = 0.8f;
static constexpr float Q_EXP = 2.0f;
static constexpr float EPS_C = 0.01f;

typedef __attribute__((ext_vector_type(8))) _Float16 half8;
typedef __attribute__((ext_vector_type(4))) _Float16 half4v;
typedef __attribute__((ext_vector_type(4))) float f32x4;

// ---------------- prep: W->fp16 (208 rows, zero pad) + counts ----------------
__global__ void k_prep(const float* __restrict__ W, const int* __restrict__ lab,
                       _Float16* __restrict__ Whf, float* __restrict__ accv){
  if (blockIdx.x == 52){
    __shared__ int cnt[CC];
    int t = threadIdx.x;
    for (int i = t; i < CC; i += 256) cnt[i] = 0;
    __syncthreads();
    for (int n = t; n < NN; n += 256) atomicAdd(&cnt[lab[n]], 1);
    __syncthreads();
    for (int i = t; i < CC; i += 256) accv[i] = fmaxf((float)cnt[i], 1.0f);
    return;
  }
  int idx = (blockIdx.x * 256 + threadIdx.x) * 4;
  if (idx >= 208 * AA) return;
  float4 w = make_float4(0.f, 0.f, 0.f, 0.f);
  if (idx < CC * AA) w = *(const float4*)(W + idx);
  Whf[idx + 0] = (_Float16)w.x;
  Whf[idx + 1] = (_Float16)w.y;
  Whf[idx + 2] = (_Float16)w.z;
  Whf[idx + 3] = (_Float16)w.w;
}

// ---------------- quadratic form + shift: one a-tile per block ----------------
// grid (16 a-tiles, 200 l) x 256 (4 waves). CV tile (16 rows x 1KB) staged to
// LDS coalesced + XOR-swizzled; all waves share A-frags. Waves split 13 c-tiles.
// chainA[ct] = sum_b CV_l[a,b] W[c,b]; accL = same with W[l,:] (broadcast).
// MFMA2: diag_c( E[c',a] * ((chainA-accL)[a,c] + 2dm[a] bcast) ) -> tbl atomics.
__global__ __launch_bounds__(256, 4) void k_quad(
    const _Float16* __restrict__ Whf, const float* __restrict__ CV,
    const float* __restrict__ ms, const float* __restrict__ mtg,
    const float* __restrict__ lamp, float* __restrict__ tbl)
{
  const int atg  = blockIdx.x;           // a-tile 0..15
  const int l    = blockIdx.y;
  const int wid  = threadIdx.x >> 6;
  const int lane = threadIdx.x & 63;
  const int lrow = lane & 15;
  const int kgrp = lane >> 4;

  __shared__ float4 cvt4[16 * 64];       // 16 rows x 64 16B-blocks = 16 KB

  // ---- stage CV tile, coalesced (1KB contiguous per wave-iter), swizzled write ----
  const size_t cvbase = (size_t)l * AA * AA + (size_t)atg * 16 * AA;
  #pragma unroll
  for (int i = 0; i < 4; ++i){
    int flat = i * 256 + threadIdx.x;    // 16B-block 0..1023; row uniform per wave
    int row  = flat >> 6;
    int c16  = flat & 63;
    float4 v = *(const float4*)(CV + cvbase + (size_t)row * AA + c16 * 4);
    cvt4[row * 64 + (c16 ^ (row & 7))] = v;
  }

  // Wl b-frags for accL (L2-hit)
  half8 wl1[8];
  #pragma unroll
  for (int kt = 0; kt < 8; ++kt)
    wl1[kt] = *(const half8*)(Whf + l * AA + kt * 32 + kgrp * 8);

  __syncthreads();

  // ---- A-frags from LDS (swizzled read), fp32->fp16 ----
  half8 cvf[8];
  #pragma unroll
  for (int kt = 0; kt < 8; ++kt){
    int j0 = kt * 8 + kgrp * 2;
    float4 v0 = cvt4[lrow * 64 + ( j0      ^ (lrow & 7))];
    float4 v1 = cvt4[lrow * 64 + ((j0 + 1) ^ (lrow & 7))];
    half8 h;
    h[0]=(_Float16)v0.x; h[1]=(_Float16)v0.y; h[2]=(_Float16)v0.z; h[3]=(_Float16)v0.w;
    h[4]=(_Float16)v1.x; h[5]=(_Float16)v1.y; h[6]=(_Float16)v1.z; h[7]=(_Float16)v1.w;
    cvf[kt] = h;
  }

  // ---- accL + this wave's ct chains: kt-outer, 5 independent MFMA chains ----
  f32x4 accL = {0.f, 0.f, 0.f, 0.f};
  f32x4 acc1[4];
  #pragma unroll
  for (int k = 0; k < 4; ++k) acc1[k] = (f32x4){0.f, 0.f, 0.f, 0.f};

  #pragma unroll
  for (int kt = 0; kt < 8; ++kt){
    accL = __builtin_amdgcn_mfma_f32_16x16x32_f16(cvf[kt], wl1[kt], accL, 0, 0, 0);
    #pragma unroll
    for (int k = 0; k < 4; ++k){
      const int ct = wid + k * 4;
      if (ct < 13){
        half8 wcf = *(const half8*)(Whf + (ct * 16 + lrow) * AA + kt * 32 + kgrp * 8);
        acc1[k] = __builtin_amdgcn_mfma_f32_16x16x32_f16(cvf[kt], wcf, acc1[k], 0, 0, 0);
      }
    }
  }

  // ---- MFMA2 diag + shift epilogue ----
  const int asl = atg * 16 + kgrp * 4;
  half4v wl2 = *(const half4v*)(Whf + l * AA + asl);
  float4 dmt = *(const float4*)(mtg + l * AA + asl);
  float4 dms = *(const float4*)(ms  + l * AA + asl);
  half4v dmf;
  dmf[0] = (_Float16)(2.f * (dmt.x - dms.x));
  dmf[1] = (_Float16)(2.f * (dmt.y - dms.y));
  dmf[2] = (_Float16)(2.f * (dmt.z - dms.z));
  dmf[3] = (_Float16)(2.f * (dmt.w - dms.w));
  const float lam = lamp[0];

  #pragma unroll
  for (int k = 0; k < 4; ++k){
    const int ct = wid + k * 4;
    if (ct < 13){
      half4v b2;
      b2[0] = (_Float16)(acc1[k][0] - accL[0]);
      b2[1] = (_Float16)(acc1[k][1] - accL[1]);
      b2[2] = (_Float16)(acc1[k][2] - accL[2]);
      b2[3] = (_Float16)(acc1[k][3] - accL[3]);
      half4v wc2 = *(const half4v*)(Whf + (ct * 16 + lrow) * AA + asl);
      half4v e2  = wc2 - wl2;
      f32x4 d2 = {0.f, 0.f, 0.f, 0.f};
      d2 = __builtin_amdgcn_mfma_f32_16x16x16f16(e2, dmf, d2, 0, 0, 0);
      d2 = __builtin_amdgcn_mfma_f32_16x16x16f16(e2, b2,  d2, 0, 0, 0);
      const int c = ct * 16 + lrow;
      if (c < CC && (lrow >> 2) == kgrp){
        const int jj = lrow & 3;
        float d = (jj == 0) ? d2[0] : (jj == 1) ? d2[1] : (jj == 2) ? d2[2] : d2[3];
        atomicAdd(&tbl[l * CC + c], 0.5f * lam * d);
      }
    }
  }
}

// ---------------- per-row seesaw loss ----------------
__global__ __launch_bounds__(64) void k_rows(
    const float* __restrict__ ys, const int* __restrict__ lab,
    const float* __restrict__ accv, const float* __restrict__ tbl,
    float* __restrict__ nll)
{
  const int n    = blockIdx.x;
  const int lane = threadIdx.x;
  const int l    = lab[n];
  const float acc_l = accv[l];
  const float log_acc_l = logf(acc_l);

  float z[4];
  float m = -1e30f;
  #pragma unroll
  for (int k = 0; k < 4; k++){
    int cidx = k * 64 + lane;
    float zz = (cidx < CC) ? (ys[n * CC + cidx] + tbl[l * CC + cidx]) : -1e30f;
    z[k] = zz;
    m = fmaxf(m, zz);
  }
  for (int o = 32; o; o >>= 1) m = fmaxf(m, __shfl_xor(m, o));

  float se = 0.f;
  #pragma unroll
  for (int k = 0; k < 4; k++){
    int cidx = k * 64 + lane;
    if (cidx < CC) se += expf(z[k] - m);
  }
  for (int o = 32; o; o >>= 1) se += __shfl_xor(se, o);
  const float L0 = m + logf(se);

  const int kl = l >> 6, ll = l & 63;
  float zsel = (kl == 0) ? z[0] : (kl == 1 ? z[1] : (kl == 2 ? z[2] : z[3]));
  const float zl = __shfl(zsel, ll);
  const float logden = fmaxf(zl - L0, logf(EPS_C));

  float lg[4];
  float m2 = -1e30f;
  #pragma unroll
  for (int k = 0; k < 4; k++){
    int cidx = k * 64 + lane;
    float lz = -1e30f;
    if (cidx < CC){
      lz = z[k];
      if (cidx != l){
        float lratio = (z[k] - L0) - logden;
        float lcomp  = (lratio > 0.f) ? Q_EXP * lratio : 0.f;
        float accc   = accv[cidx];
        float lmit   = (accc < acc_l) ? P_EXP * (logf(accc) - log_acc_l) : 0.f;
        lz += lcomp + lmit;
      }
    }
    lg[k] = lz;
    m2 = fmaxf(m2, lz);
  }
  for (int o = 32; o; o >>= 1) m2 = fmaxf(m2, __shfl_xor(m2, o));
  float se2 = 0.f;
  #pragma unroll
  for (int k = 0; k < 4; k++){
    int cidx = k * 64 + lane;
    if (cidx < CC) se2 += expf(lg[k] - m2);
  }
  for (int o = 32; o; o >>= 1) se2 += __shfl_xor(se2, o);
  const float L1 = m2 + logf(se2);

  if (lane == 0) nll[n] = L1 - zl;
}

// ---------------- mean ----------------
__global__ void k_mean(const float* __restrict__ nll, float* __restrict__ out){
  __shared__ float s[256];
  int t = threadIdx.x;
  float v = 0.f;
  for (int i = t; i < NN; i += 256) v += nll[i];
  s[t] = v; __syncthreads();
  for (int o = 128; o; o >>= 1){ if (t < o) s[t] += s[t + o]; __syncthreads(); }
  if (t == 0) out[0] = s[0] / (float)NN;
}

extern "C" void kernel_launch(void* const* d_in, const int* in_sizes, int n_in,
                              void* d_out, int out_size, void* d_ws, size_t ws_size,
                              hipStream_t stream) {
  const float* W   = (const float*)d_in[0];
  const float* ys  = (const float*)d_in[2];
  const int*   lab = (const int*)  d_in[3];
  const float* lam = (const float*)d_in[4];
  const float* ms  = (const float*)d_in[5];
  const float* mt  = (const float*)d_in[6];
  const float* CV  = (const float*)d_in[7];

  float* ws   = (float*)d_ws;
  float* tbl  = ws;                          // 40000
  float* accv = ws + 40000;                  // 256
  float* nll  = ws + 40256;                  // 1024
  _Float16* Whf = (_Float16*)(ws + 41280);   // 208*256 fp16
  float* out  = (float*)d_out;

  hipMemsetAsync(tbl, 0, CC * CC * sizeof(float), stream);
  k_prep <<<53, 256, 0, stream>>>(W, lab, Whf, accv);
  dim3 gq(16, CC);
  k_quad <<<gq, 256, 0, stream>>>(Whf, CV, ms, mt, lam, tbl);
  k_rows <<<NN, 64, 0, stream>>>(ys, lab, accv, tbl, nll);
  k_mean <<<1, 256, 0, stream>>>(nll, out);
}

// Round 8
// 85.083 us; speedup vs baseline: 1.4262x; 1.4262x over previous
//
#include <hip/hip_runtime.h>
#include <hip/hip_fp16.h>
#include <math.h>

#define NN 1024
#define CC 200
#define AA 256

static constexpr float P_EXP = 0.8f;
static constexpr float Q_EXP = 2.0f;
static constexpr float EPS_C = 0.01f;

typedef __attribute__((ext_vector_type(8))) _Float16 half8;
typedef __attribute__((ext_vector_type(4))) _Float16 half4v;
typedef __attribute__((ext_vector_type(4))) float f32x4;

// ---------------- prep: W->fp16 (208 rows, zero pad) + counts ----------------
__global__ void k_prep(const float* __restrict__ W, const int* __restrict__ lab,
                       _Float16* __restrict__ Whf, float* __restrict__ accv){
  if (blockIdx.x == 52){
    __shared__ int cnt[CC];
    int t = threadIdx.x;
    for (int i = t; i < CC; i += 256) cnt[i] = 0;
    __syncthreads();
    for (int n = t; n < NN; n += 256) atomicAdd(&cnt[lab[n]], 1);
    __syncthreads();
    for (int i = t; i < CC; i += 256) accv[i] = fmaxf((float)cnt[i], 1.0f);
    return;
  }
  int idx = (blockIdx.x * 256 + threadIdx.x) * 4;
  if (idx >= 208 * AA) return;
  float4 w = make_float4(0.f, 0.f, 0.f, 0.f);
  if (idx < CC * AA) w = *(const float4*)(W + idx);
  Whf[idx + 0] = (_Float16)w.x;
  Whf[idx + 1] = (_Float16)w.y;
  Whf[idx + 2] = (_Float16)w.z;
  Whf[idx + 3] = (_Float16)w.w;
}

// ---------------- quadratic form + shift: one a-tile per block ----------------
// grid (16 a-tiles, 200 l) x 256 (4 waves). CV tile staged to LDS as fp16
// (coalesced reads, XOR-swizzled half8 slots); all waves share A-frags.
// chainA[ct] = sum_b CV_l[a,b] W[c,b]; accL = same with W[l,:] (broadcast).
// MFMA2: diag_c( E[c',a] * ((chainA-accL)[a,c] + 2dm[a] bcast) ) -> tbl atomics.
__global__ __launch_bounds__(256) void k_quad(
    const _Float16* __restrict__ Whf, const float* __restrict__ CV,
    const float* __restrict__ ms, const float* __restrict__ mtg,
    const float* __restrict__ lamp, float* __restrict__ tbl)
{
  const int atg  = blockIdx.x;           // a-tile 0..15
  const int l    = blockIdx.y;
  const int wid  = threadIdx.x >> 6;
  const int lane = threadIdx.x & 63;
  const int lrow = lane & 15;
  const int kgrp = lane >> 4;

  __shared__ half8 cvh[16 * 32];         // 16 rows x 32 half8 slots = 8 KB

  // ---- stage CV tile -> fp16 LDS, coalesced 32B/thread, swizzled slots ----
  const size_t cvbase = (size_t)l * AA * AA + (size_t)atg * 16 * AA;
  #pragma unroll
  for (int i = 0; i < 2; ++i){
    int idx = i * 256 + threadIdx.x;     // half8 slot 0..511
    int row = idx >> 5;
    int j   = idx & 31;
    const float* p = CV + cvbase + (size_t)row * AA + j * 8;
    float4 v0 = *(const float4*)(p);
    float4 v1 = *(const float4*)(p + 4);
    half8 h;
    h[0]=(_Float16)v0.x; h[1]=(_Float16)v0.y; h[2]=(_Float16)v0.z; h[3]=(_Float16)v0.w;
    h[4]=(_Float16)v1.x; h[5]=(_Float16)v1.y; h[6]=(_Float16)v1.z; h[7]=(_Float16)v1.w;
    cvh[row * 32 + (j ^ (row & 7))] = h;
  }
  __syncthreads();

  // ---- accL + this wave's ct chains: kt-outer, 5 independent MFMA chains ----
  f32x4 accL = {0.f, 0.f, 0.f, 0.f};
  f32x4 acc1[4];
  #pragma unroll
  for (int k = 0; k < 4; ++k) acc1[k] = (f32x4){0.f, 0.f, 0.f, 0.f};

  #pragma unroll
  for (int kt = 0; kt < 8; ++kt){
    half8 cvf = cvh[lrow * 32 + ((kt * 4 + kgrp) ^ (lrow & 7))];
    half8 wl  = *(const half8*)(Whf + l * AA + kt * 32 + kgrp * 8);
    accL = __builtin_amdgcn_mfma_f32_16x16x32_f16(cvf, wl, accL, 0, 0, 0);
    #pragma unroll
    for (int k = 0; k < 4; ++k){
      const int ct = wid + k * 4;
      if (ct < 13){
        half8 wcf = *(const half8*)(Whf + (ct * 16 + lrow) * AA + kt * 32 + kgrp * 8);
        acc1[k] = __builtin_amdgcn_mfma_f32_16x16x32_f16(cvf, wcf, acc1[k], 0, 0, 0);
      }
    }
  }

  // ---- MFMA2 diag + shift epilogue ----
  const int asl = atg * 16 + kgrp * 4;
  half4v wl2 = *(const half4v*)(Whf + l * AA + asl);
  float4 dmt = *(const float4*)(mtg + l * AA + asl);
  float4 dms = *(const float4*)(ms  + l * AA + asl);
  half4v dmf;
  dmf[0] = (_Float16)(2.f * (dmt.x - dms.x));
  dmf[1] = (_Float16)(2.f * (dmt.y - dms.y));
  dmf[2] = (_Float16)(2.f * (dmt.z - dms.z));
  dmf[3] = (_Float16)(2.f * (dmt.w - dms.w));
  const float lam = lamp[0];

  #pragma unroll
  for (int k = 0; k < 4; ++k){
    const int ct = wid + k * 4;
    if (ct < 13){
      half4v b2;
      b2[0] = (_Float16)(acc1[k][0] - accL[0]);
      b2[1] = (_Float16)(acc1[k][1] - accL[1]);
      b2[2] = (_Float16)(acc1[k][2] - accL[2]);
      b2[3] = (_Float16)(acc1[k][3] - accL[3]);
      half4v wc2 = *(const half4v*)(Whf + (ct * 16 + lrow) * AA + asl);
      half4v e2  = wc2 - wl2;
      f32x4 d2 = {0.f, 0.f, 0.f, 0.f};
      d2 = __builtin_amdgcn_mfma_f32_16x16x16f16(e2, dmf, d2, 0, 0, 0);
      d2 = __builtin_amdgcn_mfma_f32_16x16x16f16(e2, b2,  d2, 0, 0, 0);
      const int c = ct * 16 + lrow;
      if (c < CC && (lrow >> 2) == kgrp){
        const int jj = lrow & 3;
        float d = (jj == 0) ? d2[0] : (jj == 1) ? d2[1] : (jj == 2) ? d2[2] : d2[3];
        atomicAdd(&tbl[l * CC + c], 0.5f * lam * d);
      }
    }
  }
}

// ---------------- per-row seesaw loss ----------------
__global__ __launch_bounds__(64) void k_rows(
    const float* __restrict__ ys, const int* __restrict__ lab,
    const float* __restrict__ accv, const float* __restrict__ tbl,
    float* __restrict__ nll)
{
  const int n    = blockIdx.x;
  const int lane = threadIdx.x;
  const int l    = lab[n];
  const float acc_l = accv[l];
  const float log_acc_l = logf(acc_l);

  float z[4];
  float m = -1e30f;
  #pragma unroll
  for (int k = 0; k < 4; k++){
    int cidx = k * 64 + lane;
    float zz = (cidx < CC) ? (ys[n * CC + cidx] + tbl[l * CC + cidx]) : -1e30f;
    z[k] = zz;
    m = fmaxf(m, zz);
  }
  for (int o = 32; o; o >>= 1) m = fmaxf(m, __shfl_xor(m, o));

  float se = 0.f;
  #pragma unroll
  for (int k = 0; k < 4; k++){
    int cidx = k * 64 + lane;
    if (cidx < CC) se += expf(z[k] - m);
  }
  for (int o = 32; o; o >>= 1) se += __shfl_xor(se, o);
  const float L0 = m + logf(se);

  const int kl = l >> 6, ll = l & 63;
  float zsel = (kl == 0) ? z[0] : (kl == 1 ? z[1] : (kl == 2 ? z[2] : z[3]));
  const float zl = __shfl(zsel, ll);
  const float logden = fmaxf(zl - L0, logf(EPS_C));

  float lg[4];
  float m2 = -1e30f;
  #pragma unroll
  for (int k = 0; k < 4; k++){
    int cidx = k * 64 + lane;
    float lz = -1e30f;
    if (cidx < CC){
      lz = z[k];
      if (cidx != l){
        float lratio = (z[k] - L0) - logden;
        float lcomp  = (lratio > 0.f) ? Q_EXP * lratio : 0.f;
        float accc   = accv[cidx];
        float lmit   = (accc < acc_l) ? P_EXP * (logf(accc) - log_acc_l) : 0.f;
        lz += lcomp + lmit;
      }
    }
    lg[k] = lz;
    m2 = fmaxf(m2, lz);
  }
  for (int o = 32; o; o >>= 1) m2 = fmaxf(m2, __shfl_xor(m2, o));
  float se2 = 0.f;
  #pragma unroll
  for (int k = 0; k < 4; k++){
    int cidx = k * 64 + lane;
    if (cidx < CC) se2 += expf(lg[k] - m2);
  }
  for (int o = 32; o; o >>= 1) se2 += __shfl_xor(se2, o);
  const float L1 = m2 + logf(se2);

  if (lane == 0) nll[n] = L1 - zl;
}

// ---------------- mean ----------------
__global__ void k_mean(const float* __restrict__ nll, float* __restrict__ out){
  __shared__ float s[256];
  int t = threadIdx.x;
  float v = 0.f;
  for (int i = t; i < NN; i += 256) v += nll[i];
  s[t] = v; __syncthreads();
  for (int o = 128; o; o >>= 1){ if (t < o) s[t] += s[t + o]; __syncthreads(); }
  if (t == 0) out[0] = s[0] / (float)NN;
}

extern "C" void kernel_launch(void* const* d_in, const int* in_sizes, int n_in,
                              void* d_out, int out_size, void* d_ws, size_t ws_size,
                              hipStream_t stream) {
  const float* W   = (const float*)d_in[0];
  const float* ys  = (const float*)d_in[2];
  const int*   lab = (const int*)  d_in[3];
  const float* lam = (const float*)d_in[4];
  const float* ms  = (const float*)d_in[5];
  const float* mt  = (const float*)d_in[6];
  const float* CV  = (const float*)d_in[7];

  float* ws   = (float*)d_ws;
  float* tbl  = ws;                          // 40000
  float* accv = ws + 40000;                  // 256
  float* nll  = ws + 40256;                  // 1024
  _Float16* Whf = (_Float16*)(ws + 41280);   // 208*256 fp16
  float* out  = (float*)d_out;

  hipMemsetAsync(tbl, 0, CC * CC * sizeof(float), stream);
  k_prep <<<53, 256, 0, stream>>>(W, lab, Whf, accv);
  dim3 gq(16, CC);
  k_quad <<<gq, 256, 0, stream>>>(Whf, CV, ms, mt, lam, tbl);
  k_rows <<<NN, 64, 0, stream>>>(ys, lab, accv, tbl, nll);
  k_mean <<<1, 256, 0, stream>>>(nll, out);
}

// Round 9
// 46.164 us; speedup vs baseline: 2.6286x; 1.8431x over previous
//
#include <hip/hip_runtime.h>
#include <hip/hip_fp16.h>
#include <math.h>

#define NN 1024
#define CC 200
#define AA 256

static constexpr float P_EXP = 0.8f;
static constexpr float Q_EXP = 2.0f;
static constexpr float EPS_C = 0.01f;

typedef __attribute__((ext_vector_type(8))) _Float16 half8;
typedef __attribute__((ext_vector_type(4))) _Float16 half4v;
typedef __attribute__((ext_vector_type(4))) float f32x4;

// ---------------- prep: W->fp16 (208 rows, zero pad) + counts ----------------
__global__ void k_prep(const float* __restrict__ W, const int* __restrict__ lab,
                       _Float16* __restrict__ Whf, float* __restrict__ accv){
  if (blockIdx.x == 52){
    __shared__ int cnt[CC];
    int t = threadIdx.x;
    for (int i = t; i < CC; i += 256) cnt[i] = 0;
    __syncthreads();
    for (int n = t; n < NN; n += 256) atomicAdd(&cnt[lab[n]], 1);
    __syncthreads();
    for (int i = t; i < CC; i += 256) accv[i] = fmaxf((float)cnt[i], 1.0f);
    return;
  }
  int idx = (blockIdx.x * 256 + threadIdx.x) * 4;
  if (idx >= 208 * AA) return;
  float4 w = make_float4(0.f, 0.f, 0.f, 0.f);
  if (idx < CC * AA) w = *(const float4*)(W + idx);
  Whf[idx + 0] = (_Float16)w.x;
  Whf[idx + 1] = (_Float16)w.y;
  Whf[idx + 2] = (_Float16)w.z;
  Whf[idx + 3] = (_Float16)w.w;
}

// ---------------- quadratic form + shift: one block per l ----------------
// 200 blocks x 512 thr (8 waves). CV_l (256KB) streamed through 2x16KB LDS
// via global_load_lds (linear dest, source-swizzled). E-frags in regs.
// MFMA1 per tile: M'[a,c] = sum_b CV[a,b]E[c,b]; MFMA2 accumulates
// diag_c( E[c',a](M'[a,c] + 2dm[a]) ) over tiles. Direct store (no atomics).
__global__ __launch_bounds__(512) void k_quad(
    const _Float16* __restrict__ Whf, const float* __restrict__ CV,
    const float* __restrict__ ms, const float* __restrict__ mtg,
    const float* __restrict__ lamp, float* __restrict__ tbl)
{
  const int l    = blockIdx.x;
  const int tid  = threadIdx.x;
  const int wid  = tid >> 6;
  const int lane = tid & 63;
  const int lrow = lane & 15;
  const int kgrp = lane >> 4;

  __shared__ float4 cvb[2][16][64];     // 2 x 16 rows x 64 16B slots = 32 KB
  __shared__ _Float16 dmh[AA];          // 2*(mt-ms) fp16

  if (tid < AA)
    dmh[tid] = (_Float16)(2.f * (mtg[l * AA + tid] - ms[l * AA + tid]));

  // ---- E fragments in registers: wave owns ct0 = wid, ct1 = wid+8 ----
  const int ct0 = wid, ct1 = wid + 8;
  half8 ef0[8], ef1[8];
  #pragma unroll
  for (int kt = 0; kt < 8; ++kt){
    half8 wlv = *(const half8*)(Whf + l * AA + kt * 32 + kgrp * 8);
    half8 wc0 = *(const half8*)(Whf + (ct0 * 16 + lrow) * AA + kt * 32 + kgrp * 8);
    ef0[kt] = wc0 - wlv;
    if (wid < 5){
      half8 wc1 = *(const half8*)(Whf + (ct1 * 16 + lrow) * AA + kt * 32 + kgrp * 8);
      ef1[kt] = wc1 - wlv;
    }
  }

  const size_t cvbase = (size_t)l * AA * AA;

  // stage tile -> buf: wave wid loads rows {2wid, 2wid+1}; LDS linear,
  // global source pre-swizzled (slot ^ (row&7)) within 128B groups.
  #define STAGE(TILE, BUF) do {                                               \
    int r0_ = wid * 2;                                                        \
    _Pragma("unroll")                                                         \
    for (int rr_ = 0; rr_ < 2; ++rr_){                                        \
      int row_ = r0_ + rr_;                                                   \
      const float* gs_ = CV + cvbase + (size_t)(TILE) * 16 * AA               \
                       + (size_t)row_ * AA + ((lane ^ (row_ & 7)) << 2);      \
      __builtin_amdgcn_global_load_lds(                                       \
        (const __attribute__((address_space(1))) void*)gs_,                   \
        (__attribute__((address_space(3))) void*)&cvb[BUF][row_][0],          \
        16, 0, 0);                                                            \
    }                                                                         \
  } while(0)

  STAGE(0, 0);
  __syncthreads();                       // tile 0 + dmh ready

  f32x4 D2a = {0.f,0.f,0.f,0.f}, D2b = {0.f,0.f,0.f,0.f};
  const float lam = lamp[0];

  for (int t = 0; t < 16; ++t){
    if (t + 1 < 16) STAGE(t + 1, (t + 1) & 1);   // async, overlaps compute

    const int buf = t & 1;
    f32x4 a0 = {0.f,0.f,0.f,0.f}, a1 = {0.f,0.f,0.f,0.f};
    #pragma unroll
    for (int kt = 0; kt < 8; ++kt){
      const int j0 = kt * 8 + kgrp * 2;
      float4 v0 = cvb[buf][lrow][( j0     ) ^ (lrow & 7)];
      float4 v1 = cvb[buf][lrow][( j0 + 1 ) ^ (lrow & 7)];
      half8 cvf;
      cvf[0]=(_Float16)v0.x; cvf[1]=(_Float16)v0.y; cvf[2]=(_Float16)v0.z; cvf[3]=(_Float16)v0.w;
      cvf[4]=(_Float16)v1.x; cvf[5]=(_Float16)v1.y; cvf[6]=(_Float16)v1.z; cvf[7]=(_Float16)v1.w;
      a0 = __builtin_amdgcn_mfma_f32_16x16x32_f16(cvf, ef0[kt], a0, 0, 0, 0);
      if (wid < 5)
        a1 = __builtin_amdgcn_mfma_f32_16x16x32_f16(cvf, ef1[kt], a1, 0, 0, 0);
    }

    // MFMA2: contract over this tile's a-slice, accumulate into D2
    half4v dmf = *(const half4v*)&dmh[t * 16 + kgrp * 4];
    half4v wl2 = *(const half4v*)(Whf + l * AA + t * 16 + kgrp * 4);
    {
      half4v wc2 = *(const half4v*)(Whf + (ct0 * 16 + lrow) * AA + t * 16 + kgrp * 4);
      half4v e2  = wc2 - wl2;
      half4v b2;
      b2[0]=(_Float16)a0[0]; b2[1]=(_Float16)a0[1]; b2[2]=(_Float16)a0[2]; b2[3]=(_Float16)a0[3];
      D2a = __builtin_amdgcn_mfma_f32_16x16x16f16(e2, b2,  D2a, 0, 0, 0);
      D2a = __builtin_amdgcn_mfma_f32_16x16x16f16(e2, dmf, D2a, 0, 0, 0);
    }
    if (wid < 5){
      half4v wc2 = *(const half4v*)(Whf + (ct1 * 16 + lrow) * AA + t * 16 + kgrp * 4);
      half4v e2  = wc2 - wl2;
      half4v b2;
      b2[0]=(_Float16)a1[0]; b2[1]=(_Float16)a1[1]; b2[2]=(_Float16)a1[2]; b2[3]=(_Float16)a1[3];
      D2b = __builtin_amdgcn_mfma_f32_16x16x16f16(e2, b2,  D2b, 0, 0, 0);
      D2b = __builtin_amdgcn_mfma_f32_16x16x16f16(e2, dmf, D2b, 0, 0, 0);
    }
    __syncthreads();                     // tile t reads done; t+1 loads drained
  }

  // diag extraction: lane holds D2[m=kgrp*4+jj][n=lrow]; diag at kgrp*4+jj==lrow
  if ((lrow >> 2) == kgrp){
    const int jj = lrow & 3;
    const int c0 = ct0 * 16 + lrow;
    float d0 = (jj == 0) ? D2a[0] : (jj == 1) ? D2a[1] : (jj == 2) ? D2a[2] : D2a[3];
    if (c0 < CC) tbl[l * CC + c0] = 0.5f * lam * d0;
    if (wid < 5){
      const int c1 = ct1 * 16 + lrow;
      float d1 = (jj == 0) ? D2b[0] : (jj == 1) ? D2b[1] : (jj == 2) ? D2b[2] : D2b[3];
      if (c1 < CC) tbl[l * CC + c1] = 0.5f * lam * d1;
    }
  }
  #undef STAGE
}

// ---------------- per-row seesaw loss ----------------
__global__ __launch_bounds__(64) void k_rows(
    const float* __restrict__ ys, const int* __restrict__ lab,
    const float* __restrict__ accv, const float* __restrict__ tbl,
    float* __restrict__ nll)
{
  const int n    = blockIdx.x;
  const int lane = threadIdx.x;
  const int l    = lab[n];
  const float acc_l = accv[l];
  const float log_acc_l = logf(acc_l);

  float z[4];
  float m = -1e30f;
  #pragma unroll
  for (int k = 0; k < 4; k++){
    int cidx = k * 64 + lane;
    float zz = (cidx < CC) ? (ys[n * CC + cidx] + tbl[l * CC + cidx]) : -1e30f;
    z[k] = zz;
    m = fmaxf(m, zz);
  }
  for (int o = 32; o; o >>= 1) m = fmaxf(m, __shfl_xor(m, o));

  float se = 0.f;
  #pragma unroll
  for (int k = 0; k < 4; k++){
    int cidx = k * 64 + lane;
    if (cidx < CC) se += expf(z[k] - m);
  }
  for (int o = 32; o; o >>= 1) se += __shfl_xor(se, o);
  const float L0 = m + logf(se);

  const int kl = l >> 6, ll = l & 63;
  float zsel = (kl == 0) ? z[0] : (kl == 1 ? z[1] : (kl == 2 ? z[2] : z[3]));
  const float zl = __shfl(zsel, ll);
  const float logden = fmaxf(zl - L0, logf(EPS_C));

  float lg[4];
  float m2 = -1e30f;
  #pragma unroll
  for (int k = 0; k < 4; k++){
    int cidx = k * 64 + lane;
    float lz = -1e30f;
    if (cidx < CC){
      lz = z[k];
      if (cidx != l){
        float lratio = (z[k] - L0) - logden;
        float lcomp  = (lratio > 0.f) ? Q_EXP * lratio : 0.f;
        float accc   = accv[cidx];
        float lmit   = (accc < acc_l) ? P_EXP * (logf(accc) - log_acc_l) : 0.f;
        lz += lcomp + lmit;
      }
    }
    lg[k] = lz;
    m2 = fmaxf(m2, lz);
  }
  for (int o = 32; o; o >>= 1) m2 = fmaxf(m2, __shfl_xor(m2, o));
  float se2 = 0.f;
  #pragma unroll
  for (int k = 0; k < 4; k++){
    int cidx = k * 64 + lane;
    if (cidx < CC) se2 += expf(lg[k] - m2);
  }
  for (int o = 32; o; o >>= 1) se2 += __shfl_xor(se2, o);
  const float L1 = m2 + logf(se2);

  if (lane == 0) nll[n] = L1 - zl;
}

// ---------------- mean ----------------
__global__ void k_mean(const float* __restrict__ nll, float* __restrict__ out){
  __shared__ float s[256];
  int t = threadIdx.x;
  float v = 0.f;
  for (int i = t; i < NN; i += 256) v += nll[i];
  s[t] = v; __syncthreads();
  for (int o = 128; o; o >>= 1){ if (t < o) s[t] += s[t + o]; __syncthreads(); }
  if (t == 0) out[0] = s[0] / (float)NN;
}

extern "C" void kernel_launch(void* const* d_in, const int* in_sizes, int n_in,
                              void* d_out, int out_size, void* d_ws, size_t ws_size,
                              hipStream_t stream) {
  const float* W   = (const float*)d_in[0];
  const float* ys  = (const float*)d_in[2];
  const int*   lab = (const int*)  d_in[3];
  const float* lam = (const float*)d_in[4];
  const float* ms  = (const float*)d_in[5];
  const float* mt  = (const float*)d_in[6];
  const float* CV  = (const float*)d_in[7];

  float* ws   = (float*)d_ws;
  float* tbl  = ws;                          // 40000 (fully overwritten)
  float* accv = ws + 40000;                  // 256
  float* nll  = ws + 40256;                  // 1024
  _Float16* Whf = (_Float16*)(ws + 41280);   // 208*256 fp16
  float* out  = (float*)d_out;

  k_prep <<<53, 256, 0, stream>>>(W, lab, Whf, accv);
  k_quad <<<CC, 512, 0, stream>>>(Whf, CV, ms, mt, lam, tbl);
  k_rows <<<NN, 64, 0, stream>>>(ys, lab, accv, tbl, nll);
  k_mean <<<1, 256, 0, stream>>>(nll, out);
}